// Round 10
// baseline (202.825 us; speedup 1.0000x reference)
//
#include <hip/hip_runtime.h>

typedef __bf16 bf16;
typedef __attribute__((ext_vector_type(8))) __bf16 bf16x8;
typedef __attribute__((ext_vector_type(4))) __bf16 bf16x4;
typedef __attribute__((ext_vector_type(4))) float f32x4;

#define MFMA16(A, B, C) __builtin_amdgcn_mfma_f32_16x16x32_bf16(A, B, C, 0, 0, 0)

// ---------------------------------------------------------------------------
// k_prep v2: re-parallelized — 224 blocks x 256, single short round.
//   blk   0..95 : weight f32->bf16 cvt (2 float4/thread)
//   blk  96..191: yu bilinear upsample (96 blocks: 8 b x 12 segs, 3 px/thread)
//   blk 192..223: gate coefficients
// ---------------------------------------------------------------------------
__global__ __launch_bounds__(256) void k_prep(
    const float* __restrict__ y, const float* __restrict__ wy, const float* __restrict__ by,
    const float* __restrict__ wq, const float* __restrict__ bq,
    const float* __restrict__ wk, const float* __restrict__ bk,
    const float* __restrict__ wv,
    bf16* __restrict__ wq_bf, bf16* __restrict__ wk_bf, bf16* __restrict__ wv_bf,
    float* __restrict__ yu, float* __restrict__ aq, float* __restrict__ cq,
    float* __restrict__ ak, float* __restrict__ ck)
{
  int blk = blockIdx.x, t = threadIdx.x;
  if (blk < 96) {
#pragma unroll
    for (int rep = 0; rep < 2; ++rep) {
      int idx4 = rep * 24576 + blk * 256 + t;
      int fo = idx4 * 4;
      const float* src; bf16* dst; int off;
      if (fo < 65536)       { src = wq; dst = wq_bf; off = fo; }
      else if (fo < 131072) { src = wk; dst = wk_bf; off = fo - 65536; }
      else                  { src = wv; dst = wv_bf; off = fo - 131072; }
      float4 v = *(const float4*)(src + off);
      bf16x4 o;
      o[0] = (bf16)v.x; o[1] = (bf16)v.y; o[2] = (bf16)v.z; o[3] = (bf16)v.w;
      *(bf16x4*)(dst + off) = o;
    }
  } else if (blk < 192) {
    // bilinear upsample y[b,1,24,24] -> yu[b,96,96], half-pixel, edge clamp
    int blkc = blk - 96;
    int b = blkc / 12, seg = blkc % 12;
    const float* yb = y + b * 576;
#pragma unroll
    for (int i = 0; i < 3; ++i) {
      int e = seg * 768 + i * 256 + t;
      int oh = e / 96, ow = e % 96;
      float sh = oh * 0.25f - 0.375f;
      float sw = ow * 0.25f - 0.375f;
      int ih0 = (int)floorf(sh);
      int iw0 = (int)floorf(sw);
      float fh = sh - (float)ih0, fw = sw - (float)iw0;
      int ih0c = min(23, max(0, ih0)), ih1c = min(23, max(0, ih0 + 1));
      int iw0c = min(23, max(0, iw0)), iw1c = min(23, max(0, iw0 + 1));
      float v00 = yb[ih0c * 24 + iw0c], v01 = yb[ih0c * 24 + iw1c];
      float v10 = yb[ih1c * 24 + iw0c], v11 = yb[ih1c * 24 + iw1c];
      yu[b * 9216 + e] = (1.0f - fh) * ((1.0f - fw) * v00 + fw * v01)
                       + fh * ((1.0f - fw) * v10 + fw * v11);
    }
  } else {
    // gate coefficients: aq = wq*wy, cq = wq*by + bq (same for k)
    int ol = t >> 5, cl = t & 31;
    int o = (blk - 192) * 8 + ol;
    int c0 = cl * 8;
    float4 wy0 = *(const float4*)(wy + c0), wy1 = *(const float4*)(wy + c0 + 4);
    float4 by0 = *(const float4*)(by + c0), by1 = *(const float4*)(by + c0 + 4);
    float4 q0  = *(const float4*)(wq + o * 256 + c0), q1 = *(const float4*)(wq + o * 256 + c0 + 4);
    float4 k0  = *(const float4*)(wk + o * 256 + c0), k1 = *(const float4*)(wk + o * 256 + c0 + 4);
    float wyv[8] = {wy0.x, wy0.y, wy0.z, wy0.w, wy1.x, wy1.y, wy1.z, wy1.w};
    float byv[8] = {by0.x, by0.y, by0.z, by0.w, by1.x, by1.y, by1.z, by1.w};
    float qv[8]  = {q0.x, q0.y, q0.z, q0.w, q1.x, q1.y, q1.z, q1.w};
    float kv[8]  = {k0.x, k0.y, k0.z, k0.w, k1.x, k1.y, k1.z, k1.w};
    float saq = 0.f, scq = 0.f, sak = 0.f, sck = 0.f;
#pragma unroll
    for (int j = 0; j < 8; ++j) {
      saq += qv[j] * wyv[j]; scq += qv[j] * byv[j];
      sak += kv[j] * wyv[j]; sck += kv[j] * byv[j];
    }
#pragma unroll
    for (int s = 16; s >= 1; s >>= 1) {
      saq += __shfl_xor(saq, s, 32);
      scq += __shfl_xor(scq, s, 32);
      sak += __shfl_xor(sak, s, 32);
      sck += __shfl_xor(sck, s, 32);
    }
    if (cl == 0) {
      aq[o] = saq; cq[o] = scq + bq[o];
      ak[o] = sak; ck[o] = sck + bk[o];
    }
  }
}

// ---------------------------------------------------------------------------
// k_fused R10 = R8 (verified best): 512 threads = 8 waves, 1 block/CU,
// 2 waves/SIMD, 256-VGPR budget (__launch_bounds__(512,2)). Each wave owns
// TWO 16-row o/d tiles (ot0 = wid*32, ot1 = ot0+16) with the FULL 256-d
// attention range: per dt the same 12 b64 K-reads + 6 b128 V-reads feed
// 24 MFMAs (2 tiles) -> K/V and P1-A LDS traffic per CU halved vs 16-wave.
// R9's manual QK/exp/PV pipeline REVERTED (it exposed K-load lgkm waits and
// spilled ~0.5 MB; compiler schedules R8's straight-line body better).
//   LDS: xs [96 w][264 c] 50688 B (-> vs), ks [256 o][104 w] 53248 B.
// ---------------------------------------------------------------------------
__global__ __launch_bounds__(512, 2) void k_fused(
    const float* __restrict__ x, const float* __restrict__ yu,
    const bf16* __restrict__ wq_bf, const bf16* __restrict__ wk_bf, const bf16* __restrict__ wv_bf,
    const float* __restrict__ bq, const float* __restrict__ bk, const float* __restrict__ bv,
    const float* __restrict__ aq, const float* __restrict__ cq,
    const float* __restrict__ ak, const float* __restrict__ ck,
    float* __restrict__ out)
{
  __shared__ __align__(16) bf16 xs[96 * 264];             // 50688 B (-> vs)
  __shared__ __align__(16) bf16 ks[256 * 104];            // 53248 B

  int pl = blockIdx.x;
  int b = pl / 96, h = pl % 96;
  int t = threadIdx.x;
  int wid = t >> 6, lane = t & 63;     // wid in [0,8)
  int l15 = lane & 15, g = lane >> 4;
  int ot0 = wid * 32;                  // this wave's two 16-row tiles
  int ot1 = wid * 32 + 16;

  const float* xrow = x + (size_t)b * 2359296 + (size_t)h * 96;

  // ---- phase 0: load x[b,:,h,:] -> xs[w][c] (bf16), 3072 tasks / 512 thr ----
#pragma unroll
  for (int i = 0; i < 6; ++i) {
    int tsk = i * 512 + t;        // 96 w x 32 cgroups
    int w = tsk % 96;
    int c0 = (tsk / 96) * 8;
    float v[8];
#pragma unroll
    for (int j = 0; j < 8; ++j) v[j] = xrow[(size_t)(c0 + j) * 9216 + w];
    bf16x8 o8;
#pragma unroll
    for (int j = 0; j < 8; ++j) o8[j] = (bf16)v[j];
    *(bf16x8*)(xs + w * 264 + c0) = o8;
  }

  // weight frags for kq=0, both tiles, issued before the barrier
  size_t woA = (size_t)(ot0 + l15) * 256 + g * 8;
  size_t woB = (size_t)(ot1 + l15) * 256 + g * 8;
  bf16x8 Bq0c = *(const bf16x8*)(wq_bf + woA);
  bf16x8 Bk0c = *(const bf16x8*)(wk_bf + woA);
  bf16x8 Bv0c = *(const bf16x8*)(wv_bf + woA);
  bf16x8 Bq1c = *(const bf16x8*)(wq_bf + woB);
  bf16x8 Bk1c = *(const bf16x8*)(wk_bf + woB);
  bf16x8 Bv1c = *(const bf16x8*)(wv_bf + woB);

  __syncthreads();

  const float SC = 0.17677669529663687f;  // 1/sqrt(32), folded into q

  bf16x8 qfA[3], qfB[3];   // pi-permuted q fragments, tiles 0 and 1

  // ---- phase 1: q,k,v projections for BOTH tiles in one pass over xs ----
  // Per kq: 6 LDS A-frags + 6 (pipelined) weight frags -> 36 MFMAs.
  {
    f32x4 qa0[6] = {}, ka0[6] = {}, va0[6] = {};
    f32x4 qa1[6] = {}, ka1[6] = {}, va1[6] = {};
#pragma unroll 1
    for (int kq = 0; kq < 8; ++kq) {
      bf16x8 Bq0n, Bk0n, Bv0n, Bq1n, Bk1n, Bv1n;
      if (kq < 7) {
        size_t a = woA + (kq + 1) * 32, bb2 = woB + (kq + 1) * 32;
        Bq0n = *(const bf16x8*)(wq_bf + a);
        Bk0n = *(const bf16x8*)(wk_bf + a);
        Bv0n = *(const bf16x8*)(wv_bf + a);
        Bq1n = *(const bf16x8*)(wq_bf + bb2);
        Bk1n = *(const bf16x8*)(wk_bf + bb2);
        Bv1n = *(const bf16x8*)(wv_bf + bb2);
      }
      const bf16* xp = xs + kq * 32 + g * 8;
      bf16x8 A[6];
#pragma unroll
      for (int m = 0; m < 6; ++m)
        A[m] = *(const bf16x8*)(xp + (m * 16 + l15) * 264);
#pragma unroll
      for (int m = 0; m < 6; ++m) {
        qa0[m] = MFMA16(A[m], Bq0c, qa0[m]);     // D[w][o]  (swapped)
        ka0[m] = MFMA16(A[m], Bk0c, ka0[m]);
        va0[m] = MFMA16(Bv0c, A[m], va0[m]);     // D[d][w]  (natural)
        qa1[m] = MFMA16(A[m], Bq1c, qa1[m]);
        ka1[m] = MFMA16(A[m], Bk1c, ka1[m]);
        va1[m] = MFMA16(Bv1c, A[m], va1[m]);
      }
      Bq0c = Bq0n; Bk0c = Bk0n; Bv0c = Bv0n;
      Bq1c = Bq1n; Bk1c = Bk1n; Bv1c = Bv1n;
    }

    // yu gate values (depend only on w, shared by both tiles)
    float4 yv[6];
    {
      const float* yr = yu + (size_t)pl * 96;
#pragma unroll
      for (int mt = 0; mt < 6; ++mt)
        yv[mt] = *(const float4*)(yr + mt * 16 + g * 4);
    }

    // per-tile epilogue of P1: qf build (pi map), k-store, V d-permuted store
    int o0 = ot0 + l15, o1 = ot1 + l15;
    float bq0 = bq[o0], aq0 = aq[o0], cq0 = cq[o0];
    float bk0 = bk[o0], ak0 = ak[o0], ck0 = ck[o0];
    float bq1 = bq[o1], aq1 = aq[o1], cq1 = cq[o1];
    float bk1 = bk[o1], ak1 = ak[o1], ck1 = ck[o1];

#pragma unroll
    for (int kk = 0; kk < 3; ++kk) {
      bf16x8 qq0, qq1;
#pragma unroll
      for (int jh = 0; jh < 2; ++jh) {
        int m = 2 * kk + jh;
        float yy[4] = {yv[m].x, yv[m].y, yv[m].z, yv[m].w};
#pragma unroll
        for (int r = 0; r < 4; ++r) {
          qq0[jh * 4 + r] = (bf16)((qa0[m][r] + bq0) * (yy[r] * aq0 + cq0) * SC);
          qq1[jh * 4 + r] = (bf16)((qa1[m][r] + bq1) * (yy[r] * aq1 + cq1) * SC);
        }
      }
      qfA[kk] = qq0;
      qfB[kk] = qq1;
    }

    // k: gate -> ks[o][w] (both tiles' 16 rows each)
#pragma unroll
    for (int m = 0; m < 6; ++m) {
      float yy[4] = {yv[m].x, yv[m].y, yv[m].z, yv[m].w};
      bf16x4 pk0, pk1;
#pragma unroll
      for (int r = 0; r < 4; ++r) {
        pk0[r] = (bf16)((ka0[m][r] + bk0) * (yy[r] * ak0 + ck0));
        pk1[r] = (bf16)((ka1[m][r] + bk1) * (yy[r] * ak1 + ck1));
      }
      *(bf16x4*)(ks + (size_t)o0 * 104 + m * 16 + g * 4) = pk0;
      *(bf16x4*)(ks + (size_t)o1 * 104 + m * 16 + g * 4) = pk1;
    }

    // v: bias; wait for ALL waves to finish reading xs, then write vs = xs.
    // D-PERMUTED store per tile: d = 32a + dn*16 + g*4 + r at
    // pos = 32a + g*8 + dn*4 + r (agrees with pa slot map = pi).
    float4 bm0 = *(const float4*)(bv + ot0 + g * 4);
    float4 bm1 = *(const float4*)(bv + ot1 + g * 4);
    float bb0[4] = {bm0.x, bm0.y, bm0.z, bm0.w};
    float bb1[4] = {bm1.x, bm1.y, bm1.z, bm1.w};
    __syncthreads();   // all xs reads done block-wide
    bf16* vs = xs;     // reuse xs as vs[w][264 dpos]
    int vb0 = (ot0 & ~16) + ((ot0 >> 2) & 4);
    int vb1 = (ot1 & ~16) + ((ot1 >> 2) & 4);
#pragma unroll
    for (int n = 0; n < 6; ++n) {
      bf16x4 pk0, pk1;
#pragma unroll
      for (int r = 0; r < 4; ++r) {
        pk0[r] = (bf16)(va0[n][r] + bb0[r]);
        pk1[r] = (bf16)(va1[n][r] + bb1[r]);
      }
      *(bf16x4*)(vs + (size_t)(n * 16 + l15) * 264 + vb0 + g * 8) = pk0;
      *(bf16x4*)(vs + (size_t)(n * 16 + l15) * 264 + vb1 + g * 8) = pk1;
    }
  }
  __syncthreads();     // ks + vs visible to all waves

  // ---- phase 4: swapped scores for both tiles -> in-register P -> P*v ----
  const bf16* vs = xs;
  f32x4 oaA[6] = {};
  f32x4 oaB[6] = {};
  float lpA = 0.f, lpB = 0.f;

  // K fragment loader (pi slot-permutation): two b64 reads 32 B apart.
  auto load_K = [&](int dt, bf16x8* K) {
    const bf16* kp = ks + (size_t)(dt * 32 + l15) * 104 + g * 4;
#pragma unroll
    for (int kk = 0; kk < 3; ++kk)
#pragma unroll
      for (int dn = 0; dn < 2; ++dn) {
        const bf16* p = kp + (size_t)(dn * 16) * 104 + kk * 32;
        bf16x4 lo = *(const bf16x4*)(p);
        bf16x4 hi = *(const bf16x4*)(p + 16);
        K[kk * 2 + dn] = __builtin_shufflevector(lo, hi, 0, 1, 2, 3, 4, 5, 6, 7);
      }
  };

  bf16x8 KA[6], KB[6];   // K-fragment double-buffer (regs)
  load_K(0, KA);

  auto attn_step = [&](int dt, bf16x8* Kc, bf16x8* Kn, bool pf) {
    int d0 = dt * 32;
    if (pf) load_K(dt + 1, Kn);
    f32x4 sA0 = {}, sA1 = {}, sB0 = {}, sB1 = {};
    __builtin_amdgcn_s_setprio(1);
#pragma unroll
    for (int kk = 0; kk < 3; ++kk) {
      sA0 = MFMA16(Kc[kk * 2 + 0], qfA[kk], sA0);   // D[m=d][n=o], tile 0
      sA1 = MFMA16(Kc[kk * 2 + 1], qfA[kk], sA1);
      sB0 = MFMA16(Kc[kk * 2 + 0], qfB[kk], sB0);   // tile 1
      sB1 = MFMA16(Kc[kk * 2 + 1], qfB[kk], sB1);
    }
    __builtin_amdgcn_s_setprio(0);
    bf16x8 paA, paB;
#pragma unroll
    for (int r = 0; r < 4; ++r) {
      float eA0 = __expf(sA0[r]), eA1 = __expf(sA1[r]);
      float eB0 = __expf(sB0[r]), eB1 = __expf(sB1[r]);
      lpA += eA0 + eA1; lpB += eB0 + eB1;
      paA[r] = (bf16)eA0; paA[4 + r] = (bf16)eA1;
      paB[r] = (bf16)eB0; paB[4 + r] = (bf16)eB1;
    }
    const bf16* vp = vs + (size_t)l15 * 264 + d0 + g * 8;
    __builtin_amdgcn_s_setprio(1);
#pragma unroll
    for (int n = 0; n < 6; ++n) {
      bf16x8 Bv = *(const bf16x8*)(vp + (size_t)n * 16 * 264);
      oaA[n] = MFMA16(paA, Bv, oaA[n]);
      oaB[n] = MFMA16(paB, Bv, oaB[n]);
    }
    __builtin_amdgcn_s_setprio(0);
  };

#pragma unroll 1
  for (int i2 = 0; i2 < 4; ++i2) {
    attn_step(2 * i2,     KA, KB, true);
    attn_step(2 * i2 + 1, KB, KA, 2 * i2 + 1 < 7);
  }

  // row-sum: lane's lp is a partial for row ot+l15; sum across g-groups
  float vA = lpA, vB = lpB;
  vA += __shfl_xor(vA, 16, 64); vA += __shfl_xor(vA, 32, 64);
  vB += __shfl_xor(vB, 16, 64); vB += __shfl_xor(vB, 32, 64);
  float invA = 1.0f / vA, invB = 1.0f / vB;
  float irA[4], irB[4];
#pragma unroll
  for (int r = 0; r < 4; ++r) {
    irA[r] = __shfl(invA, g * 4 + r, 16);
    irB[r] = __shfl(invB, g * 4 + r, 16);
  }

  // ---- epilogue: direct stores. Lane holds rows ot+4g+r at w = 16n+l15. ----
  float* ob = out + (size_t)b * 2359296 + (size_t)h * 96;
#pragma unroll
  for (int n = 0; n < 6; ++n) {
    int w = n * 16 + l15;
#pragma unroll
    for (int r = 0; r < 4; ++r) {
      int oA = ot0 + g * 4 + r;
      int oB = ot1 + g * 4 + r;
      ob[(size_t)oA * 9216 + w] = oaA[n][r] * irA[r];
      ob[(size_t)oB * 9216 + w] = oaB[n][r] * irB[r];
    }
  }
}

// ---------------------------------------------------------------------------
extern "C" void kernel_launch(void* const* d_in, const int* in_sizes, int n_in,
                              void* d_out, int out_size, void* d_ws, size_t ws_size,
                              hipStream_t stream) {
  const float* x  = (const float*)d_in[0];
  const float* y  = (const float*)d_in[1];
  const float* wy = (const float*)d_in[2];
  const float* by = (const float*)d_in[3];
  const float* wq = (const float*)d_in[4];
  const float* bq = (const float*)d_in[5];
  const float* wk = (const float*)d_in[6];
  const float* bk = (const float*)d_in[7];
  const float* wv = (const float*)d_in[8];
  const float* bv = (const float*)d_in[9];
  float* out = (float*)d_out;

  char* wsb = (char*)d_ws;
  bf16* wq_bf = (bf16*)(wsb);
  bf16* wk_bf = (bf16*)(wsb + 131072);
  bf16* wv_bf = (bf16*)(wsb + 262144);
  float* yu   = (float*)(wsb + 393216);
  float* aq   = (float*)(wsb + 688128);
  float* cq   = (float*)(wsb + 689152);
  float* ak   = (float*)(wsb + 690176);
  float* ck   = (float*)(wsb + 691200);

  hipLaunchKernelGGL(k_prep, dim3(224), dim3(256), 0, stream,
                     y, wy, by, wq, bq, wk, bk, wv,
                     wq_bf, wk_bf, wv_bf, yu, aq, cq, ak, ck);
  hipLaunchKernelGGL(k_fused, dim3(768), dim3(512), 0, stream,
                     x, yu, wq_bf, wk_bf, wv_bf, bq, bk, bv,
                     aq, cq, ak, ck, out);
}

// Round 11
// 201.707 us; speedup vs baseline: 1.0055x; 1.0055x over previous
//
#include <hip/hip_runtime.h>

typedef __bf16 bf16;
typedef __attribute__((ext_vector_type(8))) __bf16 bf16x8;
typedef __attribute__((ext_vector_type(4))) __bf16 bf16x4;
typedef __attribute__((ext_vector_type(4))) float f32x4;

#define MFMA16(A, B, C) __builtin_amdgcn_mfma_f32_16x16x32_bf16(A, B, C, 0, 0, 0)

// ---------------------------------------------------------------------------
// k_prep v2: re-parallelized — 224 blocks x 256, single short round.
//   blk   0..95 : weight f32->bf16 cvt (2 float4/thread)
//   blk  96..191: yu bilinear upsample (96 blocks: 8 b x 12 segs, 3 px/thread)
//   blk 192..223: gate coefficients
// ---------------------------------------------------------------------------
__global__ __launch_bounds__(256) void k_prep(
    const float* __restrict__ y, const float* __restrict__ wy, const float* __restrict__ by,
    const float* __restrict__ wq, const float* __restrict__ bq,
    const float* __restrict__ wk, const float* __restrict__ bk,
    const float* __restrict__ wv,
    bf16* __restrict__ wq_bf, bf16* __restrict__ wk_bf, bf16* __restrict__ wv_bf,
    float* __restrict__ yu, float* __restrict__ aq, float* __restrict__ cq,
    float* __restrict__ ak, float* __restrict__ ck)
{
  int blk = blockIdx.x, t = threadIdx.x;
  if (blk < 96) {
#pragma unroll
    for (int rep = 0; rep < 2; ++rep) {
      int idx4 = rep * 24576 + blk * 256 + t;
      int fo = idx4 * 4;
      const float* src; bf16* dst; int off;
      if (fo < 65536)       { src = wq; dst = wq_bf; off = fo; }
      else if (fo < 131072) { src = wk; dst = wk_bf; off = fo - 65536; }
      else                  { src = wv; dst = wv_bf; off = fo - 131072; }
      float4 v = *(const float4*)(src + off);
      bf16x4 o;
      o[0] = (bf16)v.x; o[1] = (bf16)v.y; o[2] = (bf16)v.z; o[3] = (bf16)v.w;
      *(bf16x4*)(dst + off) = o;
    }
  } else if (blk < 192) {
    // bilinear upsample y[b,1,24,24] -> yu[b,96,96], half-pixel, edge clamp
    int blkc = blk - 96;
    int b = blkc / 12, seg = blkc % 12;
    const float* yb = y + b * 576;
#pragma unroll
    for (int i = 0; i < 3; ++i) {
      int e = seg * 768 + i * 256 + t;
      int oh = e / 96, ow = e % 96;
      float sh = oh * 0.25f - 0.375f;
      float sw = ow * 0.25f - 0.375f;
      int ih0 = (int)floorf(sh);
      int iw0 = (int)floorf(sw);
      float fh = sh - (float)ih0, fw = sw - (float)iw0;
      int ih0c = min(23, max(0, ih0)), ih1c = min(23, max(0, ih0 + 1));
      int iw0c = min(23, max(0, iw0)), iw1c = min(23, max(0, iw0 + 1));
      float v00 = yb[ih0c * 24 + iw0c], v01 = yb[ih0c * 24 + iw1c];
      float v10 = yb[ih1c * 24 + iw0c], v11 = yb[ih1c * 24 + iw1c];
      yu[b * 9216 + e] = (1.0f - fh) * ((1.0f - fw) * v00 + fw * v01)
                       + fh * ((1.0f - fw) * v10 + fw * v11);
    }
  } else {
    // gate coefficients: aq = wq*wy, cq = wq*by + bq (same for k)
    int ol = t >> 5, cl = t & 31;
    int o = (blk - 192) * 8 + ol;
    int c0 = cl * 8;
    float4 wy0 = *(const float4*)(wy + c0), wy1 = *(const float4*)(wy + c0 + 4);
    float4 by0 = *(const float4*)(by + c0), by1 = *(const float4*)(by + c0 + 4);
    float4 q0  = *(const float4*)(wq + o * 256 + c0), q1 = *(const float4*)(wq + o * 256 + c0 + 4);
    float4 k0  = *(const float4*)(wk + o * 256 + c0), k1 = *(const float4*)(wk + o * 256 + c0 + 4);
    float wyv[8] = {wy0.x, wy0.y, wy0.z, wy0.w, wy1.x, wy1.y, wy1.z, wy1.w};
    float byv[8] = {by0.x, by0.y, by0.z, by0.w, by1.x, by1.y, by1.z, by1.w};
    float qv[8]  = {q0.x, q0.y, q0.z, q0.w, q1.x, q1.y, q1.z, q1.w};
    float kv[8]  = {k0.x, k0.y, k0.z, k0.w, k1.x, k1.y, k1.z, k1.w};
    float saq = 0.f, scq = 0.f, sak = 0.f, sck = 0.f;
#pragma unroll
    for (int j = 0; j < 8; ++j) {
      saq += qv[j] * wyv[j]; scq += qv[j] * byv[j];
      sak += kv[j] * wyv[j]; sck += kv[j] * byv[j];
    }
#pragma unroll
    for (int s = 16; s >= 1; s >>= 1) {
      saq += __shfl_xor(saq, s, 32);
      scq += __shfl_xor(scq, s, 32);
      sak += __shfl_xor(sak, s, 32);
      sck += __shfl_xor(sck, s, 32);
    }
    if (cl == 0) {
      aq[o] = saq; cq[o] = scq + bq[o];
      ak[o] = sak; ck[o] = sck + bk[o];
    }
  }
}

// ---------------------------------------------------------------------------
// k_fused R11 = R8 + pi-PACKED ks layout. K values are stored physically
// pre-permuted: K[o][w] with w = 32kk+16jh+4g'+r lives at column
// 32kk + g'*8 + jh*4 + r (bijective per 32-col chunk). The writer's bf16x4
// store stays contiguous (col (m>>1)*32 + g*8 + (m&1)*4); the P4 reader's
// fragment (slot j <-> w = 32kk+16(j>>2)+4g+(j&3), same pi as qf) becomes
// ONE aligned ds_read_b128 per (kk,dn) — 6 b128/dt instead of 12 b64 + 12
// two-register concats. Everything else identical to verified R8/R10.
//   512 thr = 8 waves, 1 block/CU, 2 waves/SIMD, 256-VGPR budget.
//   LDS: xs [96 w][264 c] 50688 B (-> vs), ks [256 o][104] 53248 B.
// ---------------------------------------------------------------------------
__global__ __launch_bounds__(512, 2) void k_fused(
    const float* __restrict__ x, const float* __restrict__ yu,
    const bf16* __restrict__ wq_bf, const bf16* __restrict__ wk_bf, const bf16* __restrict__ wv_bf,
    const float* __restrict__ bq, const float* __restrict__ bk, const float* __restrict__ bv,
    const float* __restrict__ aq, const float* __restrict__ cq,
    const float* __restrict__ ak, const float* __restrict__ ck,
    float* __restrict__ out)
{
  __shared__ __align__(16) bf16 xs[96 * 264];             // 50688 B (-> vs)
  __shared__ __align__(16) bf16 ks[256 * 104];            // 53248 B

  int pl = blockIdx.x;
  int b = pl / 96, h = pl % 96;
  int t = threadIdx.x;
  int wid = t >> 6, lane = t & 63;     // wid in [0,8)
  int l15 = lane & 15, g = lane >> 4;
  int ot0 = wid * 32;                  // this wave's two 16-row tiles
  int ot1 = wid * 32 + 16;

  const float* xrow = x + (size_t)b * 2359296 + (size_t)h * 96;

  // ---- phase 0: load x[b,:,h,:] -> xs[w][c] (bf16), 3072 tasks / 512 thr ----
#pragma unroll
  for (int i = 0; i < 6; ++i) {
    int tsk = i * 512 + t;        // 96 w x 32 cgroups
    int w = tsk % 96;
    int c0 = (tsk / 96) * 8;
    float v[8];
#pragma unroll
    for (int j = 0; j < 8; ++j) v[j] = xrow[(size_t)(c0 + j) * 9216 + w];
    bf16x8 o8;
#pragma unroll
    for (int j = 0; j < 8; ++j) o8[j] = (bf16)v[j];
    *(bf16x8*)(xs + w * 264 + c0) = o8;
  }

  // weight frags for kq=0, both tiles, issued before the barrier
  size_t woA = (size_t)(ot0 + l15) * 256 + g * 8;
  size_t woB = (size_t)(ot1 + l15) * 256 + g * 8;
  bf16x8 Bq0c = *(const bf16x8*)(wq_bf + woA);
  bf16x8 Bk0c = *(const bf16x8*)(wk_bf + woA);
  bf16x8 Bv0c = *(const bf16x8*)(wv_bf + woA);
  bf16x8 Bq1c = *(const bf16x8*)(wq_bf + woB);
  bf16x8 Bk1c = *(const bf16x8*)(wk_bf + woB);
  bf16x8 Bv1c = *(const bf16x8*)(wv_bf + woB);

  __syncthreads();

  const float SC = 0.17677669529663687f;  // 1/sqrt(32), folded into q

  bf16x8 qfA[3], qfB[3];   // pi-permuted q fragments, tiles 0 and 1

  // ---- phase 1: q,k,v projections for BOTH tiles in one pass over xs ----
  // Per kq: 6 LDS A-frags + 6 (pipelined) weight frags -> 36 MFMAs.
  {
    f32x4 qa0[6] = {}, ka0[6] = {}, va0[6] = {};
    f32x4 qa1[6] = {}, ka1[6] = {}, va1[6] = {};
#pragma unroll 1
    for (int kq = 0; kq < 8; ++kq) {
      bf16x8 Bq0n, Bk0n, Bv0n, Bq1n, Bk1n, Bv1n;
      if (kq < 7) {
        size_t a = woA + (kq + 1) * 32, bb2 = woB + (kq + 1) * 32;
        Bq0n = *(const bf16x8*)(wq_bf + a);
        Bk0n = *(const bf16x8*)(wk_bf + a);
        Bv0n = *(const bf16x8*)(wv_bf + a);
        Bq1n = *(const bf16x8*)(wq_bf + bb2);
        Bk1n = *(const bf16x8*)(wk_bf + bb2);
        Bv1n = *(const bf16x8*)(wv_bf + bb2);
      }
      const bf16* xp = xs + kq * 32 + g * 8;
      bf16x8 A[6];
#pragma unroll
      for (int m = 0; m < 6; ++m)
        A[m] = *(const bf16x8*)(xp + (m * 16 + l15) * 264);
#pragma unroll
      for (int m = 0; m < 6; ++m) {
        qa0[m] = MFMA16(A[m], Bq0c, qa0[m]);     // D[w][o]  (swapped)
        ka0[m] = MFMA16(A[m], Bk0c, ka0[m]);
        va0[m] = MFMA16(Bv0c, A[m], va0[m]);     // D[d][w]  (natural)
        qa1[m] = MFMA16(A[m], Bq1c, qa1[m]);
        ka1[m] = MFMA16(A[m], Bk1c, ka1[m]);
        va1[m] = MFMA16(Bv1c, A[m], va1[m]);
      }
      Bq0c = Bq0n; Bk0c = Bk0n; Bv0c = Bv0n;
      Bq1c = Bq1n; Bk1c = Bk1n; Bv1c = Bv1n;
    }

    // yu gate values (depend only on w, shared by both tiles)
    float4 yv[6];
    {
      const float* yr = yu + (size_t)pl * 96;
#pragma unroll
      for (int mt = 0; mt < 6; ++mt)
        yv[mt] = *(const float4*)(yr + mt * 16 + g * 4);
    }

    // per-tile epilogue of P1: qf build (pi map), k-store, V d-permuted store
    int o0 = ot0 + l15, o1 = ot1 + l15;
    float bq0 = bq[o0], aq0 = aq[o0], cq0 = cq[o0];
    float bk0 = bk[o0], ak0 = ak[o0], ck0 = ck[o0];
    float bq1 = bq[o1], aq1 = aq[o1], cq1 = cq[o1];
    float bk1 = bk[o1], ak1 = ak[o1], ck1 = ck[o1];

#pragma unroll
    for (int kk = 0; kk < 3; ++kk) {
      bf16x8 qq0, qq1;
#pragma unroll
      for (int jh = 0; jh < 2; ++jh) {
        int m = 2 * kk + jh;
        float yy[4] = {yv[m].x, yv[m].y, yv[m].z, yv[m].w};
#pragma unroll
        for (int r = 0; r < 4; ++r) {
          qq0[jh * 4 + r] = (bf16)((qa0[m][r] + bq0) * (yy[r] * aq0 + cq0) * SC);
          qq1[jh * 4 + r] = (bf16)((qa1[m][r] + bq1) * (yy[r] * aq1 + cq1) * SC);
        }
      }
      qfA[kk] = qq0;
      qfB[kk] = qq1;
    }

    // k: gate -> ks, pi-PACKED columns: value for w = m*16 + g*4 + r
    // (m = 2kk+jh) stored at col (m>>1)*32 + g*8 + (m&1)*4 + r.
#pragma unroll
    for (int m = 0; m < 6; ++m) {
      float yy[4] = {yv[m].x, yv[m].y, yv[m].z, yv[m].w};
      bf16x4 pk0, pk1;
#pragma unroll
      for (int r = 0; r < 4; ++r) {
        pk0[r] = (bf16)((ka0[m][r] + bk0) * (yy[r] * ak0 + ck0));
        pk1[r] = (bf16)((ka1[m][r] + bk1) * (yy[r] * ak1 + ck1));
      }
      int col = (m >> 1) * 32 + g * 8 + (m & 1) * 4;
      *(bf16x4*)(ks + (size_t)o0 * 104 + col) = pk0;
      *(bf16x4*)(ks + (size_t)o1 * 104 + col) = pk1;
    }

    // v: bias; wait for ALL waves to finish reading xs, then write vs = xs.
    // D-PERMUTED store per tile: d = 32a + dn*16 + g*4 + r at
    // pos = 32a + g*8 + dn*4 + r (agrees with pa slot map = pi).
    float4 bm0 = *(const float4*)(bv + ot0 + g * 4);
    float4 bm1 = *(const float4*)(bv + ot1 + g * 4);
    float bb0[4] = {bm0.x, bm0.y, bm0.z, bm0.w};
    float bb1[4] = {bm1.x, bm1.y, bm1.z, bm1.w};
    __syncthreads();   // all xs reads done block-wide
    bf16* vs = xs;     // reuse xs as vs[w][264 dpos]
    int vb0 = (ot0 & ~16) + ((ot0 >> 2) & 4);
    int vb1 = (ot1 & ~16) + ((ot1 >> 2) & 4);
#pragma unroll
    for (int n = 0; n < 6; ++n) {
      bf16x4 pk0, pk1;
#pragma unroll
      for (int r = 0; r < 4; ++r) {
        pk0[r] = (bf16)(va0[n][r] + bb0[r]);
        pk1[r] = (bf16)(va1[n][r] + bb1[r]);
      }
      *(bf16x4*)(vs + (size_t)(n * 16 + l15) * 264 + vb0 + g * 8) = pk0;
      *(bf16x4*)(vs + (size_t)(n * 16 + l15) * 264 + vb1 + g * 8) = pk1;
    }
  }
  __syncthreads();     // ks + vs visible to all waves

  // ---- phase 4: swapped scores for both tiles -> in-register P -> P*v ----
  const bf16* vs = xs;
  f32x4 oaA[6] = {};
  f32x4 oaB[6] = {};
  float lpA = 0.f, lpB = 0.f;

  // K fragment loader: pi-packed layout -> ONE b128 per (kk,dn).
  // Row = dt*32 + dn*16 + l15; cols kk*32 + g*8 .. +7. 208 B pitch, 16B-aligned.
  auto load_K = [&](int dt, bf16x8* K) {
    const bf16* kp = ks + (size_t)(dt * 32 + l15) * 104 + g * 8;
#pragma unroll
    for (int kk = 0; kk < 3; ++kk)
#pragma unroll
      for (int dn = 0; dn < 2; ++dn)
        K[kk * 2 + dn] = *(const bf16x8*)(kp + (size_t)(dn * 16) * 104 + kk * 32);
  };

  bf16x8 KA[6], KB[6];   // K-fragment double-buffer (regs)
  load_K(0, KA);

  auto attn_step = [&](int dt, bf16x8* Kc, bf16x8* Kn, bool pf) {
    int d0 = dt * 32;
    if (pf) load_K(dt + 1, Kn);
    f32x4 sA0 = {}, sA1 = {}, sB0 = {}, sB1 = {};
    __builtin_amdgcn_s_setprio(1);
#pragma unroll
    for (int kk = 0; kk < 3; ++kk) {
      sA0 = MFMA16(Kc[kk * 2 + 0], qfA[kk], sA0);   // D[m=d][n=o], tile 0
      sA1 = MFMA16(Kc[kk * 2 + 1], qfA[kk], sA1);
      sB0 = MFMA16(Kc[kk * 2 + 0], qfB[kk], sB0);   // tile 1
      sB1 = MFMA16(Kc[kk * 2 + 1], qfB[kk], sB1);
    }
    __builtin_amdgcn_s_setprio(0);
    bf16x8 paA, paB;
#pragma unroll
    for (int r = 0; r < 4; ++r) {
      float eA0 = __expf(sA0[r]), eA1 = __expf(sA1[r]);
      float eB0 = __expf(sB0[r]), eB1 = __expf(sB1[r]);
      lpA += eA0 + eA1; lpB += eB0 + eB1;
      paA[r] = (bf16)eA0; paA[4 + r] = (bf16)eA1;
      paB[r] = (bf16)eB0; paB[4 + r] = (bf16)eB1;
    }
    const bf16* vp = vs + (size_t)l15 * 264 + d0 + g * 8;
    __builtin_amdgcn_s_setprio(1);
#pragma unroll
    for (int n = 0; n < 6; ++n) {
      bf16x8 Bv = *(const bf16x8*)(vp + (size_t)n * 16 * 264);
      oaA[n] = MFMA16(paA, Bv, oaA[n]);
      oaB[n] = MFMA16(paB, Bv, oaB[n]);
    }
    __builtin_amdgcn_s_setprio(0);
  };

#pragma unroll 1
  for (int i2 = 0; i2 < 4; ++i2) {
    attn_step(2 * i2,     KA, KB, true);
    attn_step(2 * i2 + 1, KB, KA, 2 * i2 + 1 < 7);
  }

  // row-sum: lane's lp is a partial for row ot+l15; sum across g-groups
  float vA = lpA, vB = lpB;
  vA += __shfl_xor(vA, 16, 64); vA += __shfl_xor(vA, 32, 64);
  vB += __shfl_xor(vB, 16, 64); vB += __shfl_xor(vB, 32, 64);
  float invA = 1.0f / vA, invB = 1.0f / vB;
  float irA[4], irB[4];
#pragma unroll
  for (int r = 0; r < 4; ++r) {
    irA[r] = __shfl(invA, g * 4 + r, 16);
    irB[r] = __shfl(invB, g * 4 + r, 16);
  }

  // ---- epilogue: direct stores. Lane holds rows ot+4g+r at w = 16n+l15. ----
  float* ob = out + (size_t)b * 2359296 + (size_t)h * 96;
#pragma unroll
  for (int n = 0; n < 6; ++n) {
    int w = n * 16 + l15;
#pragma unroll
    for (int r = 0; r < 4; ++r) {
      int oA = ot0 + g * 4 + r;
      int oB = ot1 + g * 4 + r;
      ob[(size_t)oA * 9216 + w] = oaA[n][r] * irA[r];
      ob[(size_t)oB * 9216 + w] = oaB[n][r] * irB[r];
    }
  }
}

// ---------------------------------------------------------------------------
extern "C" void kernel_launch(void* const* d_in, const int* in_sizes, int n_in,
                              void* d_out, int out_size, void* d_ws, size_t ws_size,
                              hipStream_t stream) {
  const float* x  = (const float*)d_in[0];
  const float* y  = (const float*)d_in[1];
  const float* wy = (const float*)d_in[2];
  const float* by = (const float*)d_in[3];
  const float* wq = (const float*)d_in[4];
  const float* bq = (const float*)d_in[5];
  const float* wk = (const float*)d_in[6];
  const float* bk = (const float*)d_in[7];
  const float* wv = (const float*)d_in[8];
  const float* bv = (const float*)d_in[9];
  float* out = (float*)d_out;

  char* wsb = (char*)d_ws;
  bf16* wq_bf = (bf16*)(wsb);
  bf16* wk_bf = (bf16*)(wsb + 131072);
  bf16* wv_bf = (bf16*)(wsb + 262144);
  float* yu   = (float*)(wsb + 393216);
  float* aq   = (float*)(wsb + 688128);
  float* cq   = (float*)(wsb + 689152);
  float* ak   = (float*)(wsb + 690176);
  float* ck   = (float*)(wsb + 691200);

  hipLaunchKernelGGL(k_prep, dim3(224), dim3(256), 0, stream,
                     y, wy, by, wq, bq, wk, bk, wv,
                     wq_bf, wk_bf, wv_bf, yu, aq, cq, ak, ck);
  hipLaunchKernelGGL(k_fused, dim3(768), dim3(512), 0, stream,
                     x, yu, wq_bf, wk_bf, wv_bf, bq, bk, bv,
                     aq, cq, ak, ck, out);
}